// Round 1
// baseline (4300.234 us; speedup 1.0000x reference)
//
#include <hip/hip_runtime.h>
#include <hip/hip_bf16.h>

#define TOK 16384
#define TAU 0.025f

typedef __attribute__((ext_vector_type(8))) short short8;
typedef __attribute__((ext_vector_type(4))) float f32x4;

__device__ __forceinline__ unsigned short f32_bf16(float f) {
  __hip_bfloat16 h = __float2bfloat16(f);
  unsigned short u;
  __builtin_memcpy(&u, &h, sizeof(u));
  return u;
}
__device__ __forceinline__ float bf16_f32(unsigned short u) {
  union { unsigned int i; float f; } c; c.i = ((unsigned int)u) << 16; return c.f;
}

__global__ void zero_int(int* p) { if (threadIdx.x == 0) *p = 0; }

__global__ void cvt_kernel(const float* __restrict__ s, unsigned short* __restrict__ d, int n4) {
  int i = blockIdx.x * 256 + threadIdx.x;
  if (i < n4) {
    float4 v = ((const float4*)s)[i];
    union { unsigned short u[4]; uint2 q; } pk;
    pk.u[0] = f32_bf16(v.x); pk.u[1] = f32_bf16(v.y);
    pk.u[2] = f32_bf16(v.z); pk.u[3] = f32_bf16(v.w);
    ((uint2*)d)[i] = pk.q;
  }
}

// C[M,N] = A[M,K] * Bw[N,K]^T  (+bias, epilogue variants)
// AMODE: 0 = fp32 A (convert on the fly), 1 = fp32 A scaled per row-half (selector),
//        2 = bf16 A direct
// EPI:   0 = bias -> bf16 store, 1 = relu(bias) -> bf16 store,
//        2 = bias -> fp32 store to out iff sel[row]==branch
template<int AMODE, int EPI>
__global__ __launch_bounds__(256, 2)
void gemm_tile(const void* __restrict__ Av,
               const unsigned short* __restrict__ Bw,
               const float* __restrict__ bias,
               void* __restrict__ Outv,
               const int* __restrict__ sel, int branch,
               const float* __restrict__ scA, const float* __restrict__ scB,
               int M, int N, int K) {
  __shared__ __align__(16) unsigned short As[128 * 32];
  __shared__ __align__(16) unsigned short Bs[128 * 32];
  const int tid = threadIdx.x;
  const int m0 = blockIdx.y * 128, n0 = blockIdx.x * 128;
  const int lane = tid & 63, wave = tid >> 6;
  const int wm = wave >> 1, wn = wave & 1;
  const int quad = lane >> 4, lr = lane & 15;
  const int srow = tid >> 1, scol = (tid & 1) * 16;

  f32x4 acc[4][4] = {};

  for (int k0 = 0; k0 < K; k0 += 32) {
    // ---- stage A tile [128][32]
    if (AMODE == 2) {
      const unsigned short* A = (const unsigned short*)Av;
      const uint4* src = (const uint4*)(A + (size_t)(m0 + srow) * K + k0 + scol);
      uint4* dst = (uint4*)(As + srow * 32 + scol);
      dst[0] = src[0]; dst[1] = src[1];
    } else {
      const float* A = (const float*)Av;
      const float4* src = (const float4*)(A + (size_t)(m0 + srow) * K + k0 + scol);
      float4 f[4];
      f[0] = src[0]; f[1] = src[1]; f[2] = src[2]; f[3] = src[3];
      float s = 1.0f;
      if (AMODE == 1) {
        int tk = m0 + srow;
        s = ((k0 + scol) * 2 < K) ? scA[tk] : scB[tk];
      }
      union { unsigned short u[16]; uint4 q[2]; } pk;
      const float* ff = (const float*)f;
      #pragma unroll
      for (int e = 0; e < 16; e++) {
        float fv = ff[e];
        if (AMODE == 1) fv *= s;
        pk.u[e] = f32_bf16(fv);
      }
      uint4* dst = (uint4*)(As + srow * 32 + scol);
      dst[0] = pk.q[0]; dst[1] = pk.q[1];
    }
    // ---- stage B tile [128][32] (bf16 weights, row-major [N,K])
    {
      const uint4* src = (const uint4*)(Bw + (size_t)(n0 + srow) * K + k0 + scol);
      uint4* dst = (uint4*)(Bs + srow * 32 + scol);
      dst[0] = src[0]; dst[1] = src[1];
    }
    __syncthreads();
    short8 af[4], bfr[4];
    #pragma unroll
    for (int i = 0; i < 4; i++)
      af[i] = *(const short8*)(As + (wm * 64 + i * 16 + lr) * 32 + quad * 8);
    #pragma unroll
    for (int j = 0; j < 4; j++)
      bfr[j] = *(const short8*)(Bs + (wn * 64 + j * 16 + lr) * 32 + quad * 8);
    #pragma unroll
    for (int i = 0; i < 4; i++)
      #pragma unroll
      for (int j = 0; j < 4; j++)
        acc[i][j] = __builtin_amdgcn_mfma_f32_16x16x32_bf16(af[i], bfr[j], acc[i][j], 0, 0, 0);
    __syncthreads();
  }

  // ---- epilogue: C/D layout col=lane&15 (n), row=quad*4+reg (m)
  #pragma unroll
  for (int i = 0; i < 4; i++) {
    const int rbase = m0 + wm * 64 + i * 16 + quad * 4;
    #pragma unroll
    for (int j = 0; j < 4; j++) {
      const int col = n0 + wn * 64 + j * 16 + lr;
      const float bv = bias[col];
      #pragma unroll
      for (int r = 0; r < 4; r++) {
        const int row = rbase + r;
        float v = acc[i][j][r] + bv;
        if (EPI == 0) {
          ((unsigned short*)Outv)[(size_t)row * N + col] = f32_bf16(v);
        } else if (EPI == 1) {
          ((unsigned short*)Outv)[(size_t)row * N + col] = f32_bf16(fmaxf(v, 0.0f));
        } else {
          if (sel[row] == branch) ((float*)Outv)[(size_t)row * N + col] = v;
        }
      }
    }
  }
}

// logits from bf16 hid, argmax + margin flagging. One wave per token.
__global__ __launch_bounds__(256)
void selector_logits(const unsigned short* __restrict__ hid,
                     const float* __restrict__ W2, const float* __restrict__ b2,
                     int* __restrict__ sel, int* __restrict__ risky,
                     int* __restrict__ riskyCount) {
  const int wave = threadIdx.x >> 6, lane = threadIdx.x & 63;
  const int token = blockIdx.x * 4 + wave;
  union { uint4 q; unsigned short u[8]; } hq;
  hq.q = *(const uint4*)(hid + (size_t)token * 512 + lane * 8);
  float hv[8];
  #pragma unroll
  for (int e = 0; e < 8; e++) hv[e] = bf16_f32(hq.u[e]);
  float p[3];
  #pragma unroll
  for (int c = 0; c < 3; c++) {
    const float* w = W2 + c * 512 + lane * 8;
    float4 w0 = *(const float4*)w, w1 = *(const float4*)(w + 4);
    p[c] = hv[0]*w0.x + hv[1]*w0.y + hv[2]*w0.z + hv[3]*w0.w
         + hv[4]*w1.x + hv[5]*w1.y + hv[6]*w1.z + hv[7]*w1.w;
  }
  #pragma unroll
  for (int off = 32; off >= 1; off >>= 1) {
    #pragma unroll
    for (int c = 0; c < 3; c++) p[c] += __shfl_xor(p[c], off, 64);
  }
  if (lane == 0) {
    float l0 = p[0] + b2[0], l1 = p[1] + b2[1], l2 = p[2] + b2[2];
    int arg = 0; float best = l0;
    if (l1 > best) { best = l1; arg = 1; }
    if (l2 > best) { best = l2; arg = 2; }
    float second;
    if (arg == 0) second = fmaxf(l1, l2);
    else if (arg == 1) second = fmaxf(l0, l2);
    else second = fmaxf(l0, l1);
    sel[token] = arg;
    if (best - second < TAU) {
      int idx = atomicAdd(riskyCount, 1);
      risky[idx] = token;
    }
  }
}

// full-fp32 recompute of the selector for flagged near-tie tokens.
// 8 tokens per block; 32 threads per token.
__global__ __launch_bounds__(256)
void recheck(const float* __restrict__ h, const float* __restrict__ freq,
             const float* __restrict__ imp,
             const float* __restrict__ W1, const float* __restrict__ b1,
             const float* __restrict__ W2, const float* __restrict__ b2,
             const int* __restrict__ risky, const int* __restrict__ riskyCount,
             int* __restrict__ sel) {
  __shared__ float hid_sh[8][512];
  const int g = threadIdx.x >> 5, j = threadIdx.x & 31;
  const int n = *riskyCount;
  for (int base = blockIdx.x * 8; base < n; base += gridDim.x * 8) {
    const int ti = base + g;
    const int token = (ti < n) ? risky[ti] : -1;
    if (token >= 0) {
      const float f = freq[token], pim = imp[token];
      const float* hrow = h + (size_t)token * 2048;
      for (int oo = 0; oo < 16; oo++) {
        const int o = j + oo * 32;
        const float* wrow = W1 + (size_t)o * 2048;
        float acc = 0.0f;
        for (int k = 0; k < 1024; k += 4) {
          float4 a = *(const float4*)(hrow + k);
          float4 w = *(const float4*)(wrow + k);
          acc += f * (a.x*w.x + a.y*w.y + a.z*w.z + a.w*w.w);
        }
        for (int k = 1024; k < 2048; k += 4) {
          float4 a = *(const float4*)(hrow + k);
          float4 w = *(const float4*)(wrow + k);
          acc += pim * (a.x*w.x + a.y*w.y + a.z*w.z + a.w*w.w);
        }
        hid_sh[g][o] = fmaxf(acc + b1[o], 0.0f);
      }
    }
    __syncthreads();
    if (token >= 0) {
      float l[3];
      #pragma unroll
      for (int c = 0; c < 3; c++) {
        const float* w2 = W2 + c * 512 + j * 16;
        const float* hs = &hid_sh[g][j * 16];
        float s = 0.0f;
        #pragma unroll
        for (int o = 0; o < 16; o++) s += hs[o] * w2[o];
        l[c] = s;
      }
      #pragma unroll
      for (int off = 16; off >= 1; off >>= 1) {
        #pragma unroll
        for (int c = 0; c < 3; c++) l[c] += __shfl_xor(l[c], off, 64);
      }
      if (j == 0) {
        float l0 = l[0] + b2[0], l1 = l[1] + b2[1], l2 = l[2] + b2[2];
        int arg = 0; float best = l0;
        if (l1 > best) { best = l1; arg = 1; }
        if (l2 > best) { arg = 2; }
        sel[token] = arg;
      }
    }
    __syncthreads();
  }
}

__global__ __launch_bounds__(256)
void copy_sel0(const float* __restrict__ h, const int* __restrict__ sel,
               float* __restrict__ out) {
  const int token = blockIdx.x;
  if (sel[token] != 0) return;
  const float4* src = (const float4*)(h + (size_t)token * 2048);
  float4* dst = (float4*)(out + (size_t)token * 2048);
  dst[threadIdx.x] = src[threadIdx.x];
  dst[threadIdx.x + 256] = src[threadIdx.x + 256];
}

extern "C" void kernel_launch(void* const* d_in, const int* in_sizes, int n_in,
                              void* d_out, int out_size, void* d_ws, size_t ws_size,
                              hipStream_t stream) {
  const float* h        = (const float*)d_in[0];
  const float* freq     = (const float*)d_in[1];
  const float* imp      = (const float*)d_in[2];
  const float* comp1W   = (const float*)d_in[3];
  const float* comp1b   = (const float*)d_in[4];
  const float* adapt1W  = (const float*)d_in[5];
  const float* adapt1b  = (const float*)d_in[6];
  const float* decomp1W = (const float*)d_in[7];
  const float* decomp1b = (const float*)d_in[8];
  const float* comp2W   = (const float*)d_in[9];
  const float* comp2b   = (const float*)d_in[10];
  const float* adapt2W  = (const float*)d_in[11];
  const float* adapt2b  = (const float*)d_in[12];
  const float* decomp2W = (const float*)d_in[13];
  const float* decomp2b = (const float*)d_in[14];
  const float* sel1W    = (const float*)d_in[15];
  const float* sel1b    = (const float*)d_in[16];
  const float* sel2W    = (const float*)d_in[17];
  const float* sel2b    = (const float*)d_in[18];
  float* out = (float*)d_out;

  char* ws = (char*)d_ws;
  size_t off = 0;
  auto alloc = [&](size_t bytes) -> void* {
    void* p = ws + off; off += (bytes + 255) & ~(size_t)255; return p;
  };
  unsigned short* wb_comp1   = (unsigned short*)alloc((size_t)1024 * 2048 * 2);
  unsigned short* wb_adapt1  = (unsigned short*)alloc((size_t)1024 * 1024 * 2);
  unsigned short* wb_decomp1 = (unsigned short*)alloc((size_t)2048 * 1024 * 2);
  unsigned short* wb_comp2   = (unsigned short*)alloc((size_t)512 * 2048 * 2);
  unsigned short* wb_adapt2  = (unsigned short*)alloc((size_t)512 * 512 * 2);
  unsigned short* wb_decomp2 = (unsigned short*)alloc((size_t)2048 * 512 * 2);
  unsigned short* wb_sel1    = (unsigned short*)alloc((size_t)512 * 2048 * 2);
  unsigned short* hid        = (unsigned short*)alloc((size_t)TOK * 512 * 2);
  unsigned short* c1         = (unsigned short*)alloc((size_t)TOK * 1024 * 2);
  unsigned short* a1         = (unsigned short*)alloc((size_t)TOK * 1024 * 2);
  int* sel        = (int*)alloc((size_t)TOK * 4);
  int* risky      = (int*)alloc((size_t)TOK * 4);
  int* riskyCount = (int*)alloc(256);
  unsigned short* c2 = c1;   // branch 2 runs after branch 1 finished
  unsigned short* a2 = a1;

  zero_int<<<1, 64, 0, stream>>>(riskyCount);

  auto cvt = [&](const float* s, unsigned short* d, int n) {
    cvt_kernel<<<(n / 4 + 255) / 256, 256, 0, stream>>>(s, d, n / 4);
  };
  cvt(comp1W,   wb_comp1,   1024 * 2048);
  cvt(adapt1W,  wb_adapt1,  1024 * 1024);
  cvt(decomp1W, wb_decomp1, 2048 * 1024);
  cvt(comp2W,   wb_comp2,   512 * 2048);
  cvt(adapt2W,  wb_adapt2,  512 * 512);
  cvt(decomp2W, wb_decomp2, 2048 * 512);
  cvt(sel1W,    wb_sel1,    512 * 2048);

  // selector: hid = relu(combined @ sel1W^T + b)   (scaling fused into A staging)
  gemm_tile<1, 1><<<dim3(512 / 128, TOK / 128), 256, 0, stream>>>(
      h, wb_sel1, sel1b, hid, nullptr, 0, freq, imp, TOK, 512, 2048);
  selector_logits<<<TOK / 4, 256, 0, stream>>>(hid, sel2W, sel2b, sel, risky, riskyCount);
  recheck<<<160, 256, 0, stream>>>(h, freq, imp, sel1W, sel1b, sel2W, sel2b,
                                   risky, riskyCount, sel);

  // branch 1: H -> H/2 -> H/2 -> H, predicated store for sel==1
  gemm_tile<0, 0><<<dim3(1024 / 128, TOK / 128), 256, 0, stream>>>(
      h, wb_comp1, comp1b, c1, nullptr, 0, nullptr, nullptr, TOK, 1024, 2048);
  gemm_tile<2, 0><<<dim3(1024 / 128, TOK / 128), 256, 0, stream>>>(
      c1, wb_adapt1, adapt1b, a1, nullptr, 0, nullptr, nullptr, TOK, 1024, 1024);
  gemm_tile<2, 2><<<dim3(2048 / 128, TOK / 128), 256, 0, stream>>>(
      a1, wb_decomp1, decomp1b, out, sel, 1, nullptr, nullptr, TOK, 2048, 1024);

  // branch 2: H -> H/4 -> H/4 -> H, predicated store for sel==2
  gemm_tile<0, 0><<<dim3(512 / 128, TOK / 128), 256, 0, stream>>>(
      h, wb_comp2, comp2b, c2, nullptr, 0, nullptr, nullptr, TOK, 512, 2048);
  gemm_tile<2, 0><<<dim3(512 / 128, TOK / 128), 256, 0, stream>>>(
      c2, wb_adapt2, adapt2b, a2, nullptr, 0, nullptr, nullptr, TOK, 512, 512);
  gemm_tile<2, 2><<<dim3(2048 / 128, TOK / 128), 256, 0, stream>>>(
      a2, wb_decomp2, decomp2b, out, sel, 2, nullptr, nullptr, TOK, 2048, 512);

  // sel==0 tokens: exact fp32 passthrough of h
  copy_sel0<<<TOK, 256, 0, stream>>>(h, sel, out);
}

// Round 2
// 1721.222 us; speedup vs baseline: 2.4984x; 2.4984x over previous
//
#include <hip/hip_runtime.h>
#include <hip/hip_bf16.h>

#define TOK 16384
#define TAU 0.025f

typedef __attribute__((ext_vector_type(8))) short short8;
typedef __attribute__((ext_vector_type(4))) float f32x4;

__device__ __forceinline__ unsigned short f32_bf16(float f) {
  __hip_bfloat16 h = __float2bfloat16(f);
  unsigned short u;
  __builtin_memcpy(&u, &h, sizeof(u));
  return u;
}
__device__ __forceinline__ float bf16_f32(unsigned short u) {
  union { unsigned int i; float f; } c; c.i = ((unsigned int)u) << 16; return c.f;
}

__global__ void zero_int(int* p) { if (threadIdx.x == 0) *p = 0; }

__global__ void cvt_kernel(const float* __restrict__ s, unsigned short* __restrict__ d, int n4) {
  int i = blockIdx.x * 256 + threadIdx.x;
  if (i < n4) {
    float4 v = ((const float4*)s)[i];
    union { unsigned short u[4]; uint2 q; } pk;
    pk.u[0] = f32_bf16(v.x); pk.u[1] = f32_bf16(v.y);
    pk.u[2] = f32_bf16(v.z); pk.u[3] = f32_bf16(v.w);
    ((uint2*)d)[i] = pk.q;
  }
}

// C[M,N] = A[M,K] * Bw[N,K]^T  (+bias, epilogue variants)
// AMODE: 0 = fp32 A (convert on the fly), 1 = fp32 A scaled per row-half (selector),
//        2 = bf16 A direct
// EPI:   0 = bias -> bf16 store, 1 = relu(bias) -> bf16 store,
//        2 = bias -> fp32 store to out iff sel[row]==branch
template<int AMODE, int EPI>
__global__ __launch_bounds__(256, 2)
void gemm_tile(const void* __restrict__ Av,
               const unsigned short* __restrict__ Bw,
               const float* __restrict__ bias,
               void* __restrict__ Outv,
               const int* __restrict__ sel, int branch,
               const float* __restrict__ scA, const float* __restrict__ scB,
               int M, int N, int K) {
  __shared__ __align__(16) unsigned short As[128 * 32];
  __shared__ __align__(16) unsigned short Bs[128 * 32];
  const int tid = threadIdx.x;
  const int m0 = blockIdx.y * 128, n0 = blockIdx.x * 128;
  const int lane = tid & 63, wave = tid >> 6;
  const int wm = wave >> 1, wn = wave & 1;
  const int quad = lane >> 4, lr = lane & 15;
  const int srow = tid >> 1, scol = (tid & 1) * 16;

  f32x4 acc[4][4] = {};

  for (int k0 = 0; k0 < K; k0 += 32) {
    // ---- stage A tile [128][32]
    if (AMODE == 2) {
      const unsigned short* A = (const unsigned short*)Av;
      const uint4* src = (const uint4*)(A + (size_t)(m0 + srow) * K + k0 + scol);
      uint4* dst = (uint4*)(As + srow * 32 + scol);
      dst[0] = src[0]; dst[1] = src[1];
    } else {
      const float* A = (const float*)Av;
      const float4* src = (const float4*)(A + (size_t)(m0 + srow) * K + k0 + scol);
      float4 f[4];
      f[0] = src[0]; f[1] = src[1]; f[2] = src[2]; f[3] = src[3];
      float s = 1.0f;
      if (AMODE == 1) {
        int tk = m0 + srow;
        s = ((k0 + scol) * 2 < K) ? scA[tk] : scB[tk];
      }
      union { unsigned short u[16]; uint4 q[2]; } pk;
      const float* ff = (const float*)f;
      #pragma unroll
      for (int e = 0; e < 16; e++) {
        float fv = ff[e];
        if (AMODE == 1) fv *= s;
        pk.u[e] = f32_bf16(fv);
      }
      uint4* dst = (uint4*)(As + srow * 32 + scol);
      dst[0] = pk.q[0]; dst[1] = pk.q[1];
    }
    // ---- stage B tile [128][32] (bf16 weights, row-major [N,K])
    {
      const uint4* src = (const uint4*)(Bw + (size_t)(n0 + srow) * K + k0 + scol);
      uint4* dst = (uint4*)(Bs + srow * 32 + scol);
      dst[0] = src[0]; dst[1] = src[1];
    }
    __syncthreads();
    short8 af[4], bfr[4];
    #pragma unroll
    for (int i = 0; i < 4; i++)
      af[i] = *(const short8*)(As + (wm * 64 + i * 16 + lr) * 32 + quad * 8);
    #pragma unroll
    for (int j = 0; j < 4; j++)
      bfr[j] = *(const short8*)(Bs + (wn * 64 + j * 16 + lr) * 32 + quad * 8);
    #pragma unroll
    for (int i = 0; i < 4; i++)
      #pragma unroll
      for (int j = 0; j < 4; j++)
        acc[i][j] = __builtin_amdgcn_mfma_f32_16x16x32_bf16(af[i], bfr[j], acc[i][j], 0, 0, 0);
    __syncthreads();
  }

  // ---- epilogue: C/D layout col=lane&15 (n), row=quad*4+reg (m)
  #pragma unroll
  for (int i = 0; i < 4; i++) {
    const int rbase = m0 + wm * 64 + i * 16 + quad * 4;
    #pragma unroll
    for (int j = 0; j < 4; j++) {
      const int col = n0 + wn * 64 + j * 16 + lr;
      const float bv = bias[col];
      #pragma unroll
      for (int r = 0; r < 4; r++) {
        const int row = rbase + r;
        float v = acc[i][j][r] + bv;
        if (EPI == 0) {
          ((unsigned short*)Outv)[(size_t)row * N + col] = f32_bf16(v);
        } else if (EPI == 1) {
          ((unsigned short*)Outv)[(size_t)row * N + col] = f32_bf16(fmaxf(v, 0.0f));
        } else {
          if (sel[row] == branch) ((float*)Outv)[(size_t)row * N + col] = v;
        }
      }
    }
  }
}

// logits from bf16 hid, argmax + margin flagging. One wave per token.
__global__ __launch_bounds__(256)
void selector_logits(const unsigned short* __restrict__ hid,
                     const float* __restrict__ W2, const float* __restrict__ b2,
                     int* __restrict__ sel, int* __restrict__ risky,
                     int* __restrict__ riskyCount) {
  const int wave = threadIdx.x >> 6, lane = threadIdx.x & 63;
  const int token = blockIdx.x * 4 + wave;
  union { uint4 q; unsigned short u[8]; } hq;
  hq.q = *(const uint4*)(hid + (size_t)token * 512 + lane * 8);
  float hv[8];
  #pragma unroll
  for (int e = 0; e < 8; e++) hv[e] = bf16_f32(hq.u[e]);
  float p[3];
  #pragma unroll
  for (int c = 0; c < 3; c++) {
    const float* w = W2 + c * 512 + lane * 8;
    float4 w0 = *(const float4*)w, w1 = *(const float4*)(w + 4);
    p[c] = hv[0]*w0.x + hv[1]*w0.y + hv[2]*w0.z + hv[3]*w0.w
         + hv[4]*w1.x + hv[5]*w1.y + hv[6]*w1.z + hv[7]*w1.w;
  }
  #pragma unroll
  for (int off = 32; off >= 1; off >>= 1) {
    #pragma unroll
    for (int c = 0; c < 3; c++) p[c] += __shfl_xor(p[c], off, 64);
  }
  if (lane == 0) {
    float l0 = p[0] + b2[0], l1 = p[1] + b2[1], l2 = p[2] + b2[2];
    int arg = 0; float best = l0;
    if (l1 > best) { best = l1; arg = 1; }
    if (l2 > best) { best = l2; arg = 2; }
    float second;
    if (arg == 0) second = fmaxf(l1, l2);
    else if (arg == 1) second = fmaxf(l0, l2);
    else second = fmaxf(l0, l1);
    sel[token] = arg;
    if (best - second < TAU) {
      int idx = atomicAdd(riskyCount, 1);
      risky[idx] = token;
    }
  }
}

// full-fp32 recompute of the selector for flagged near-tie tokens.
// 4 tokens per block; h rows staged in LDS then hoisted to registers;
// W1 rows read fully coalesced; wave-per-output with shuffle reduce.
__global__ __launch_bounds__(256)
void recheck(const float* __restrict__ h, const float* __restrict__ freq,
             const float* __restrict__ imp,
             const float* __restrict__ W1, const float* __restrict__ b1,
             const float* __restrict__ W2, const float* __restrict__ b2,
             const int* __restrict__ risky, const int* __restrict__ riskyCount,
             int* __restrict__ sel) {
  __shared__ float h_sh[4][2048];    // 32 KB
  __shared__ float hid_sh[4][512];   // 8 KB
  const int n = *riskyCount;
  const int tid = threadIdx.x, lane = tid & 63, wave = tid >> 6;
  for (int base = blockIdx.x * 4; base < n; base += gridDim.x * 4) {
    // ---- stage 4 pre-scaled fp32 h rows into LDS (coalesced)
    #pragma unroll
    for (int t = 0; t < 4; t++) {
      const int ti = base + t;
      if (ti < n) {
        const int token = risky[ti];
        const float s = (tid < 128) ? freq[token] : imp[token];
        const float4* src = (const float4*)(h + (size_t)token * 2048) + tid * 2;
        float4 v0 = src[0], v1 = src[1];
        v0.x *= s; v0.y *= s; v0.z *= s; v0.w *= s;
        v1.x *= s; v1.y *= s; v1.z *= s; v1.w *= s;
        float4* dst = ((float4*)h_sh[t]) + tid * 2;
        dst[0] = v0; dst[1] = v1;
      }
    }
    __syncthreads();
    // ---- hoist this lane's k-slice of all 4 h rows into registers.
    // lane covers k in {q*256 + lane*4 .. +4} for q=0..7  (32 floats x 4 tokens)
    float4 hreg[8][4];
    #pragma unroll
    for (int q = 0; q < 8; q++)
      #pragma unroll
      for (int t = 0; t < 4; t++)
        hreg[q][t] = ((const float4*)&h_sh[t][q * 256])[lane];
    // ---- hid: wave handles outputs [wave*128, wave*128+128)
    for (int oi = 0; oi < 128; oi++) {
      const int o = wave * 128 + oi;
      const float4* wrow = (const float4*)(W1 + (size_t)o * 2048);
      float a[4] = {0.0f, 0.0f, 0.0f, 0.0f};
      #pragma unroll
      for (int q = 0; q < 8; q++) {
        const float4 wv = wrow[q * 64 + lane];   // coalesced 1KB/instr
        #pragma unroll
        for (int t = 0; t < 4; t++) {
          const float4 hv = hreg[q][t];
          a[t] += wv.x * hv.x + wv.y * hv.y + wv.z * hv.z + wv.w * hv.w;
        }
      }
      #pragma unroll
      for (int off = 32; off >= 1; off >>= 1)
        #pragma unroll
        for (int t = 0; t < 4; t++) a[t] += __shfl_xor(a[t], off, 64);
      if (lane == 0) {
        #pragma unroll
        for (int t = 0; t < 4; t++)
          hid_sh[t][o] = fmaxf(a[t] + b1[o], 0.0f);
      }
    }
    __syncthreads();
    // ---- logits layer: wave t handles token base+t
    {
      const int ti = base + wave;
      if (ti < n) {
        const float* hs = &hid_sh[wave][lane * 8];
        float hv[8];
        #pragma unroll
        for (int e = 0; e < 8; e++) hv[e] = hs[e];
        float l[3];
        #pragma unroll
        for (int c = 0; c < 3; c++) {
          const float* w = W2 + c * 512 + lane * 8;
          float s = 0.0f;
          #pragma unroll
          for (int e = 0; e < 8; e++) s += hv[e] * w[e];
          l[c] = s;
        }
        #pragma unroll
        for (int off = 32; off >= 1; off >>= 1)
          #pragma unroll
          for (int c = 0; c < 3; c++) l[c] += __shfl_xor(l[c], off, 64);
        if (lane == 0) {
          float l0 = l[0] + b2[0], l1 = l[1] + b2[1], l2 = l[2] + b2[2];
          int arg = 0; float best = l0;
          if (l1 > best) { best = l1; arg = 1; }
          if (l2 > best) { arg = 2; }
          sel[risky[ti]] = arg;
        }
      }
    }
    __syncthreads();
  }
}

__global__ __launch_bounds__(256)
void copy_sel0(const float* __restrict__ h, const int* __restrict__ sel,
               float* __restrict__ out) {
  const int token = blockIdx.x;
  if (sel[token] != 0) return;
  const float4* src = (const float4*)(h + (size_t)token * 2048);
  float4* dst = (float4*)(out + (size_t)token * 2048);
  dst[threadIdx.x] = src[threadIdx.x];
  dst[threadIdx.x + 256] = src[threadIdx.x + 256];
}

extern "C" void kernel_launch(void* const* d_in, const int* in_sizes, int n_in,
                              void* d_out, int out_size, void* d_ws, size_t ws_size,
                              hipStream_t stream) {
  const float* h        = (const float*)d_in[0];
  const float* freq     = (const float*)d_in[1];
  const float* imp      = (const float*)d_in[2];
  const float* comp1W   = (const float*)d_in[3];
  const float* comp1b   = (const float*)d_in[4];
  const float* adapt1W  = (const float*)d_in[5];
  const float* adapt1b  = (const float*)d_in[6];
  const float* decomp1W = (const float*)d_in[7];
  const float* decomp1b = (const float*)d_in[8];
  const float* comp2W   = (const float*)d_in[9];
  const float* comp2b   = (const float*)d_in[10];
  const float* adapt2W  = (const float*)d_in[11];
  const float* adapt2b  = (const float*)d_in[12];
  const float* decomp2W = (const float*)d_in[13];
  const float* decomp2b = (const float*)d_in[14];
  const float* sel1W    = (const float*)d_in[15];
  const float* sel1b    = (const float*)d_in[16];
  const float* sel2W    = (const float*)d_in[17];
  const float* sel2b    = (const float*)d_in[18];
  float* out = (float*)d_out;

  char* ws = (char*)d_ws;
  size_t off = 0;
  auto alloc = [&](size_t bytes) -> void* {
    void* p = ws + off; off += (bytes + 255) & ~(size_t)255; return p;
  };
  unsigned short* wb_comp1   = (unsigned short*)alloc((size_t)1024 * 2048 * 2);
  unsigned short* wb_adapt1  = (unsigned short*)alloc((size_t)1024 * 1024 * 2);
  unsigned short* wb_decomp1 = (unsigned short*)alloc((size_t)2048 * 1024 * 2);
  unsigned short* wb_comp2   = (unsigned short*)alloc((size_t)512 * 2048 * 2);
  unsigned short* wb_adapt2  = (unsigned short*)alloc((size_t)512 * 512 * 2);
  unsigned short* wb_decomp2 = (unsigned short*)alloc((size_t)2048 * 512 * 2);
  unsigned short* wb_sel1    = (unsigned short*)alloc((size_t)512 * 2048 * 2);
  unsigned short* hid        = (unsigned short*)alloc((size_t)TOK * 512 * 2);
  unsigned short* c1         = (unsigned short*)alloc((size_t)TOK * 1024 * 2);
  unsigned short* a1         = (unsigned short*)alloc((size_t)TOK * 1024 * 2);
  int* sel        = (int*)alloc((size_t)TOK * 4);
  int* risky      = (int*)alloc((size_t)TOK * 4);
  int* riskyCount = (int*)alloc(256);
  unsigned short* c2 = c1;   // branch 2 runs after branch 1 finished
  unsigned short* a2 = a1;

  zero_int<<<1, 64, 0, stream>>>(riskyCount);

  auto cvt = [&](const float* s, unsigned short* d, int n) {
    cvt_kernel<<<(n / 4 + 255) / 256, 256, 0, stream>>>(s, d, n / 4);
  };
  cvt(comp1W,   wb_comp1,   1024 * 2048);
  cvt(adapt1W,  wb_adapt1,  1024 * 1024);
  cvt(decomp1W, wb_decomp1, 2048 * 1024);
  cvt(comp2W,   wb_comp2,   512 * 2048);
  cvt(adapt2W,  wb_adapt2,  512 * 512);
  cvt(decomp2W, wb_decomp2, 2048 * 512);
  cvt(sel1W,    wb_sel1,    512 * 2048);

  // selector: hid = relu(combined @ sel1W^T + b)   (scaling fused into A staging)
  gemm_tile<1, 1><<<dim3(512 / 128, TOK / 128), 256, 0, stream>>>(
      h, wb_sel1, sel1b, hid, nullptr, 0, freq, imp, TOK, 512, 2048);
  selector_logits<<<TOK / 4, 256, 0, stream>>>(hid, sel2W, sel2b, sel, risky, riskyCount);
  recheck<<<1024, 256, 0, stream>>>(h, freq, imp, sel1W, sel1b, sel2W, sel2b,
                                    risky, riskyCount, sel);

  // branch 1: H -> H/2 -> H/2 -> H, predicated store for sel==1
  gemm_tile<0, 0><<<dim3(1024 / 128, TOK / 128), 256, 0, stream>>>(
      h, wb_comp1, comp1b, c1, nullptr, 0, nullptr, nullptr, TOK, 1024, 2048);
  gemm_tile<2, 0><<<dim3(1024 / 128, TOK / 128), 256, 0, stream>>>(
      c1, wb_adapt1, adapt1b, a1, nullptr, 0, nullptr, nullptr, TOK, 1024, 1024);
  gemm_tile<2, 2><<<dim3(2048 / 128, TOK / 128), 256, 0, stream>>>(
      a1, wb_decomp1, decomp1b, out, sel, 1, nullptr, nullptr, TOK, 2048, 1024);

  // branch 2: H -> H/4 -> H/4 -> H, predicated store for sel==2
  gemm_tile<0, 0><<<dim3(512 / 128, TOK / 128), 256, 0, stream>>>(
      h, wb_comp2, comp2b, c2, nullptr, 0, nullptr, nullptr, TOK, 512, 2048);
  gemm_tile<2, 0><<<dim3(512 / 128, TOK / 128), 256, 0, stream>>>(
      c2, wb_adapt2, adapt2b, a2, nullptr, 0, nullptr, nullptr, TOK, 512, 512);
  gemm_tile<2, 2><<<dim3(2048 / 128, TOK / 128), 256, 0, stream>>>(
      a2, wb_decomp2, decomp2b, out, sel, 2, nullptr, nullptr, TOK, 2048, 512);

  // sel==0 tokens: exact fp32 passthrough of h
  copy_sel0<<<TOK, 256, 0, stream>>>(h, sel, out);
}

// Round 3
// 1055.510 us; speedup vs baseline: 4.0741x; 1.6307x over previous
//
#include <hip/hip_runtime.h>
#include <hip/hip_bf16.h>

#define TOK 16384
#define TAU2 0.001f

typedef __attribute__((ext_vector_type(8))) short short8;
typedef __attribute__((ext_vector_type(4))) float f32x4;

__device__ __forceinline__ unsigned short f32_bf16(float f) {
  __hip_bfloat16 h = __float2bfloat16(f);
  unsigned short u;
  __builtin_memcpy(&u, &h, sizeof(u));
  return u;
}
__device__ __forceinline__ float bf16_f32(unsigned short u) {
  union { unsigned int i; float f; } c; c.i = ((unsigned int)u) << 16; return c.f;
}

__global__ void zero_int(int* p) { if (threadIdx.x == 0) *p = 0; }

__global__ void cvt_kernel(const float* __restrict__ s, unsigned short* __restrict__ d, int n4) {
  int i = blockIdx.x * 256 + threadIdx.x;
  if (i < n4) {
    float4 v = ((const float4*)s)[i];
    union { unsigned short u[4]; uint2 q; } pk;
    pk.u[0] = f32_bf16(v.x); pk.u[1] = f32_bf16(v.y);
    pk.u[2] = f32_bf16(v.z); pk.u[3] = f32_bf16(v.w);
    ((uint2*)d)[i] = pk.q;
  }
}

// split fp32 -> (hi, lo) bf16 pair: hi = bf16(v), lo = bf16(v - f32(hi))
__global__ void cvt_split_kernel(const float* __restrict__ s,
                                 unsigned short* __restrict__ dhi,
                                 unsigned short* __restrict__ dlo, int n4) {
  int i = blockIdx.x * 256 + threadIdx.x;
  if (i < n4) {
    float4 v = ((const float4*)s)[i];
    const float* f = (const float*)&v;
    union { unsigned short u[4]; uint2 q; } hi, lo;
    #pragma unroll
    for (int e = 0; e < 4; e++) {
      unsigned short h = f32_bf16(f[e]);
      hi.u[e] = h;
      lo.u[e] = f32_bf16(f[e] - bf16_f32(h));
    }
    ((uint2*)dhi)[i] = hi.q;
    ((uint2*)dlo)[i] = lo.q;
  }
}

// C[M,N] = A[M,K] * Bw[N,K]^T  (+bias, epilogue variants)
// AMODE: 0 = fp32 A (convert on the fly), 2 = bf16 A direct,
//        3 = fp32 A scaled per row-half, SPLIT hi/lo; B split (Bw=hi, Bw2=lo);
//            3 MFMAs per fragment pair (near-fp32 product accuracy)
// EPI:   0 = bias -> bf16 store, 1 = relu(bias) -> bf16 store,
//        2 = bias -> fp32 store to out iff sel[row]==branch,
//        3 = relu(bias) -> fp32 store
template<int AMODE, int EPI>
__global__ __launch_bounds__(256, 2)
void gemm_tile(const void* __restrict__ Av,
               const unsigned short* __restrict__ Bw,
               const unsigned short* __restrict__ Bw2,
               const float* __restrict__ bias,
               void* __restrict__ Outv,
               const int* __restrict__ sel, int branch,
               const float* __restrict__ scA, const float* __restrict__ scB,
               int M, int N, int K) {
  __shared__ __align__(16) unsigned short As[(AMODE == 3 ? 2 : 1) * 128 * 32];
  __shared__ __align__(16) unsigned short Bs[(AMODE == 3 ? 2 : 1) * 128 * 32];
  const int LO = 128 * 32;  // offset of lo-half when AMODE==3
  const int tid = threadIdx.x;
  const int m0 = blockIdx.y * 128, n0 = blockIdx.x * 128;
  const int lane = tid & 63, wave = tid >> 6;
  const int wm = wave >> 1, wn = wave & 1;
  const int quad = lane >> 4, lr = lane & 15;
  const int srow = tid >> 1, scol = (tid & 1) * 16;

  f32x4 acc[4][4] = {};

  for (int k0 = 0; k0 < K; k0 += 32) {
    // ---- stage A tile [128][32]
    if (AMODE == 2) {
      const unsigned short* A = (const unsigned short*)Av;
      const uint4* src = (const uint4*)(A + (size_t)(m0 + srow) * K + k0 + scol);
      uint4* dst = (uint4*)(As + srow * 32 + scol);
      dst[0] = src[0]; dst[1] = src[1];
    } else {
      const float* A = (const float*)Av;
      const float4* src = (const float4*)(A + (size_t)(m0 + srow) * K + k0 + scol);
      float4 f[4];
      f[0] = src[0]; f[1] = src[1]; f[2] = src[2]; f[3] = src[3];
      float s = 1.0f;
      if (AMODE == 3) {
        int tk = m0 + srow;
        s = ((k0 + scol) * 2 < K) ? scA[tk] : scB[tk];
      }
      union { unsigned short u[16]; uint4 q[2]; } hi;
      union { unsigned short u[16]; uint4 q[2]; } lo;
      const float* ff = (const float*)f;
      #pragma unroll
      for (int e = 0; e < 16; e++) {
        float fv = ff[e];
        if (AMODE == 3) fv *= s;
        unsigned short hb = f32_bf16(fv);
        hi.u[e] = hb;
        if (AMODE == 3) lo.u[e] = f32_bf16(fv - bf16_f32(hb));
      }
      uint4* dst = (uint4*)(As + srow * 32 + scol);
      dst[0] = hi.q[0]; dst[1] = hi.q[1];
      if (AMODE == 3) {
        uint4* dst2 = (uint4*)(As + LO + srow * 32 + scol);
        dst2[0] = lo.q[0]; dst2[1] = lo.q[1];
      }
    }
    // ---- stage B tile [128][32] (bf16 weights, row-major [N,K])
    {
      const uint4* src = (const uint4*)(Bw + (size_t)(n0 + srow) * K + k0 + scol);
      uint4* dst = (uint4*)(Bs + srow * 32 + scol);
      dst[0] = src[0]; dst[1] = src[1];
      if (AMODE == 3) {
        const uint4* src2 = (const uint4*)(Bw2 + (size_t)(n0 + srow) * K + k0 + scol);
        uint4* dst2 = (uint4*)(Bs + LO + srow * 32 + scol);
        dst2[0] = src2[0]; dst2[1] = src2[1];
      }
    }
    __syncthreads();
    short8 af[4], bfr[4];
    #pragma unroll
    for (int i = 0; i < 4; i++)
      af[i] = *(const short8*)(As + (wm * 64 + i * 16 + lr) * 32 + quad * 8);
    #pragma unroll
    for (int j = 0; j < 4; j++)
      bfr[j] = *(const short8*)(Bs + (wn * 64 + j * 16 + lr) * 32 + quad * 8);
    if (AMODE == 3) {
      short8 af2[4], bf2[4];
      #pragma unroll
      for (int i = 0; i < 4; i++)
        af2[i] = *(const short8*)(As + LO + (wm * 64 + i * 16 + lr) * 32 + quad * 8);
      #pragma unroll
      for (int j = 0; j < 4; j++)
        bf2[j] = *(const short8*)(Bs + LO + (wn * 64 + j * 16 + lr) * 32 + quad * 8);
      #pragma unroll
      for (int i = 0; i < 4; i++)
        #pragma unroll
        for (int j = 0; j < 4; j++) {
          acc[i][j] = __builtin_amdgcn_mfma_f32_16x16x32_bf16(af[i], bfr[j], acc[i][j], 0, 0, 0);
          acc[i][j] = __builtin_amdgcn_mfma_f32_16x16x32_bf16(af[i], bf2[j], acc[i][j], 0, 0, 0);
          acc[i][j] = __builtin_amdgcn_mfma_f32_16x16x32_bf16(af2[i], bfr[j], acc[i][j], 0, 0, 0);
        }
    } else {
      #pragma unroll
      for (int i = 0; i < 4; i++)
        #pragma unroll
        for (int j = 0; j < 4; j++)
          acc[i][j] = __builtin_amdgcn_mfma_f32_16x16x32_bf16(af[i], bfr[j], acc[i][j], 0, 0, 0);
    }
    __syncthreads();
  }

  // ---- epilogue: C/D layout col=lane&15 (n), row=quad*4+reg (m)
  #pragma unroll
  for (int i = 0; i < 4; i++) {
    const int rbase = m0 + wm * 64 + i * 16 + quad * 4;
    #pragma unroll
    for (int j = 0; j < 4; j++) {
      const int col = n0 + wn * 64 + j * 16 + lr;
      const float bv = bias[col];
      #pragma unroll
      for (int r = 0; r < 4; r++) {
        const int row = rbase + r;
        float v = acc[i][j][r] + bv;
        if (EPI == 0) {
          ((unsigned short*)Outv)[(size_t)row * N + col] = f32_bf16(v);
        } else if (EPI == 1) {
          ((unsigned short*)Outv)[(size_t)row * N + col] = f32_bf16(fmaxf(v, 0.0f));
        } else if (EPI == 2) {
          if (sel[row] == branch) ((float*)Outv)[(size_t)row * N + col] = v;
        } else {
          ((float*)Outv)[(size_t)row * N + col] = fmaxf(v, 0.0f);
        }
      }
    }
  }
}

// logits from fp32 hid (split-GEMM output), argmax + tight margin flagging.
// One wave per token.
__global__ __launch_bounds__(256)
void selector_logits_f32(const float* __restrict__ hidf,
                         const float* __restrict__ W2, const float* __restrict__ b2,
                         int* __restrict__ sel, int* __restrict__ risky,
                         int* __restrict__ riskyCount) {
  const int wave = threadIdx.x >> 6, lane = threadIdx.x & 63;
  const int token = blockIdx.x * 4 + wave;
  const float* hs = hidf + (size_t)token * 512 + lane * 8;
  float4 h0 = *(const float4*)hs, h1 = *(const float4*)(hs + 4);
  float p[3];
  #pragma unroll
  for (int c = 0; c < 3; c++) {
    const float* w = W2 + c * 512 + lane * 8;
    float4 w0 = *(const float4*)w, w1 = *(const float4*)(w + 4);
    p[c] = h0.x*w0.x + h0.y*w0.y + h0.z*w0.z + h0.w*w0.w
         + h1.x*w1.x + h1.y*w1.y + h1.z*w1.z + h1.w*w1.w;
  }
  #pragma unroll
  for (int off = 32; off >= 1; off >>= 1) {
    #pragma unroll
    for (int c = 0; c < 3; c++) p[c] += __shfl_xor(p[c], off, 64);
  }
  if (lane == 0) {
    float l0 = p[0] + b2[0], l1 = p[1] + b2[1], l2 = p[2] + b2[2];
    int arg = 0; float best = l0;
    if (l1 > best) { best = l1; arg = 1; }
    if (l2 > best) { best = l2; arg = 2; }
    float second;
    if (arg == 0) second = fmaxf(l1, l2);
    else if (arg == 1) second = fmaxf(l0, l2);
    else second = fmaxf(l0, l1);
    sel[token] = arg;
    if (best - second < TAU2) {
      int idx = atomicAdd(riskyCount, 1);
      risky[idx] = token;
    }
  }
}

// exact fp32 selector recompute for ultra-near-tie tokens (~100 expected).
// One block per token: h staged in LDS (broadcast reads), thread-per-output
// with 4-way ILP accumulators. No shuffle chains in the hot loop.
__global__ __launch_bounds__(256)
void recheck_exact(const float* __restrict__ h, const float* __restrict__ freq,
                   const float* __restrict__ imp,
                   const float* __restrict__ W1, const float* __restrict__ b1,
                   const float* __restrict__ W2, const float* __restrict__ b2,
                   const int* __restrict__ risky, const int* __restrict__ riskyCount,
                   int* __restrict__ sel) {
  __shared__ float h_sh[2048];
  __shared__ float hid_sh[512];
  const int n = *riskyCount;
  const int tid = threadIdx.x;
  for (int ri = blockIdx.x; ri < n; ri += gridDim.x) {
    const int token = risky[ri];
    {
      const float s = (tid < 128) ? freq[token] : imp[token];
      const float4* src = (const float4*)(h + (size_t)token * 2048) + tid * 2;
      float4 v0 = src[0], v1 = src[1];
      v0.x *= s; v0.y *= s; v0.z *= s; v0.w *= s;
      v1.x *= s; v1.y *= s; v1.z *= s; v1.w *= s;
      ((float4*)h_sh)[tid * 2] = v0;
      ((float4*)h_sh)[tid * 2 + 1] = v1;
    }
    __syncthreads();
    #pragma unroll
    for (int half = 0; half < 2; half++) {
      const int o = tid + half * 256;
      const float* wrow = W1 + (size_t)o * 2048;
      float a0 = 0.f, a1 = 0.f, a2 = 0.f, a3 = 0.f;
      for (int k = 0; k < 2048; k += 16) {
        float4 w0 = *(const float4*)(wrow + k);
        float4 w1v = *(const float4*)(wrow + k + 4);
        float4 w2v = *(const float4*)(wrow + k + 8);
        float4 w3v = *(const float4*)(wrow + k + 12);
        float4 x0 = *(const float4*)(h_sh + k);
        float4 x1 = *(const float4*)(h_sh + k + 4);
        float4 x2 = *(const float4*)(h_sh + k + 8);
        float4 x3 = *(const float4*)(h_sh + k + 12);
        a0 += w0.x*x0.x + w0.y*x0.y + w0.z*x0.z + w0.w*x0.w;
        a1 += w1v.x*x1.x + w1v.y*x1.y + w1v.z*x1.z + w1v.w*x1.w;
        a2 += w2v.x*x2.x + w2v.y*x2.y + w2v.z*x2.z + w2v.w*x2.w;
        a3 += w3v.x*x3.x + w3v.y*x3.y + w3v.z*x3.z + w3v.w*x3.w;
      }
      hid_sh[o] = fmaxf((a0 + a1) + (a2 + a3) + b1[o], 0.0f);
    }
    __syncthreads();
    if (tid < 64) {
      const int lane = tid;
      const float* hs = &hid_sh[lane * 8];
      float l[3];
      #pragma unroll
      for (int c = 0; c < 3; c++) {
        const float* w = W2 + c * 512 + lane * 8;
        float s = 0.0f;
        #pragma unroll
        for (int e = 0; e < 8; e++) s += hs[e] * w[e];
        l[c] = s;
      }
      #pragma unroll
      for (int off = 32; off >= 1; off >>= 1)
        #pragma unroll
        for (int c = 0; c < 3; c++) l[c] += __shfl_xor(l[c], off, 64);
      if (lane == 0) {
        float l0 = l[0] + b2[0], l1 = l[1] + b2[1], l2 = l[2] + b2[2];
        int arg = 0; float best = l0;
        if (l1 > best) { best = l1; arg = 1; }
        if (l2 > best) { arg = 2; }
        sel[token] = arg;
      }
    }
    __syncthreads();
  }
}

__global__ __launch_bounds__(256)
void copy_sel0(const float* __restrict__ h, const int* __restrict__ sel,
               float* __restrict__ out) {
  const int token = blockIdx.x;
  if (sel[token] != 0) return;
  const float4* src = (const float4*)(h + (size_t)token * 2048);
  float4* dst = (float4*)(out + (size_t)token * 2048);
  dst[threadIdx.x] = src[threadIdx.x];
  dst[threadIdx.x + 256] = src[threadIdx.x + 256];
}

extern "C" void kernel_launch(void* const* d_in, const int* in_sizes, int n_in,
                              void* d_out, int out_size, void* d_ws, size_t ws_size,
                              hipStream_t stream) {
  const float* h        = (const float*)d_in[0];
  const float* freq     = (const float*)d_in[1];
  const float* imp      = (const float*)d_in[2];
  const float* comp1W   = (const float*)d_in[3];
  const float* comp1b   = (const float*)d_in[4];
  const float* adapt1W  = (const float*)d_in[5];
  const float* adapt1b  = (const float*)d_in[6];
  const float* decomp1W = (const float*)d_in[7];
  const float* decomp1b = (const float*)d_in[8];
  const float* comp2W   = (const float*)d_in[9];
  const float* comp2b   = (const float*)d_in[10];
  const float* adapt2W  = (const float*)d_in[11];
  const float* adapt2b  = (const float*)d_in[12];
  const float* decomp2W = (const float*)d_in[13];
  const float* decomp2b = (const float*)d_in[14];
  const float* sel1W    = (const float*)d_in[15];
  const float* sel1b    = (const float*)d_in[16];
  const float* sel2W    = (const float*)d_in[17];
  const float* sel2b    = (const float*)d_in[18];
  float* out = (float*)d_out;

  char* ws = (char*)d_ws;
  size_t off = 0;
  auto alloc = [&](size_t bytes) -> void* {
    void* p = ws + off; off += (bytes + 255) & ~(size_t)255; return p;
  };
  unsigned short* wb_comp1   = (unsigned short*)alloc((size_t)1024 * 2048 * 2);
  unsigned short* wb_adapt1  = (unsigned short*)alloc((size_t)1024 * 1024 * 2);
  unsigned short* wb_decomp1 = (unsigned short*)alloc((size_t)2048 * 1024 * 2);
  unsigned short* wb_comp2   = (unsigned short*)alloc((size_t)512 * 2048 * 2);
  unsigned short* wb_adapt2  = (unsigned short*)alloc((size_t)512 * 512 * 2);
  unsigned short* wb_decomp2 = (unsigned short*)alloc((size_t)2048 * 512 * 2);
  unsigned short* w1hi       = (unsigned short*)alloc((size_t)512 * 2048 * 2);
  unsigned short* w1lo       = (unsigned short*)alloc((size_t)512 * 2048 * 2);
  float*          hidf       = (float*)alloc((size_t)TOK * 512 * 4);
  unsigned short* c1         = (unsigned short*)alloc((size_t)TOK * 1024 * 2);
  unsigned short* a1         = (unsigned short*)alloc((size_t)TOK * 1024 * 2);
  int* sel        = (int*)alloc((size_t)TOK * 4);
  int* risky      = (int*)alloc((size_t)TOK * 4);
  int* riskyCount = (int*)alloc(256);
  unsigned short* c2 = c1;   // branch 2 runs after branch 1 finished
  unsigned short* a2 = a1;

  zero_int<<<1, 64, 0, stream>>>(riskyCount);

  auto cvt = [&](const float* s, unsigned short* d, int n) {
    cvt_kernel<<<(n / 4 + 255) / 256, 256, 0, stream>>>(s, d, n / 4);
  };
  cvt(comp1W,   wb_comp1,   1024 * 2048);
  cvt(adapt1W,  wb_adapt1,  1024 * 1024);
  cvt(decomp1W, wb_decomp1, 2048 * 1024);
  cvt(comp2W,   wb_comp2,   512 * 2048);
  cvt(adapt2W,  wb_adapt2,  512 * 512);
  cvt(decomp2W, wb_decomp2, 2048 * 512);
  cvt_split_kernel<<<(512 * 2048 / 4 + 255) / 256, 256, 0, stream>>>(
      sel1W, w1hi, w1lo, 512 * 2048 / 4);

  // selector: hid = relu(combined @ sel1W^T + b) in split-bf16 (near-fp32), fp32 store
  gemm_tile<3, 3><<<dim3(512 / 128, TOK / 128), 256, 0, stream>>>(
      h, w1hi, w1lo, sel1b, hidf, nullptr, 0, freq, imp, TOK, 512, 2048);
  selector_logits_f32<<<TOK / 4, 256, 0, stream>>>(hidf, sel2W, sel2b, sel, risky, riskyCount);
  recheck_exact<<<256, 256, 0, stream>>>(h, freq, imp, sel1W, sel1b, sel2W, sel2b,
                                         risky, riskyCount, sel);

  // branch 1: H -> H/2 -> H/2 -> H, predicated store for sel==1
  gemm_tile<0, 0><<<dim3(1024 / 128, TOK / 128), 256, 0, stream>>>(
      h, wb_comp1, nullptr, comp1b, c1, nullptr, 0, nullptr, nullptr, TOK, 1024, 2048);
  gemm_tile<2, 0><<<dim3(1024 / 128, TOK / 128), 256, 0, stream>>>(
      c1, wb_adapt1, nullptr, adapt1b, a1, nullptr, 0, nullptr, nullptr, TOK, 1024, 1024);
  gemm_tile<2, 2><<<dim3(2048 / 128, TOK / 128), 256, 0, stream>>>(
      a1, wb_decomp1, nullptr, decomp1b, out, sel, 1, nullptr, nullptr, TOK, 2048, 1024);

  // branch 2: H -> H/4 -> H/4 -> H, predicated store for sel==2
  gemm_tile<0, 0><<<dim3(512 / 128, TOK / 128), 256, 0, stream>>>(
      h, wb_comp2, nullptr, comp2b, c2, nullptr, 0, nullptr, nullptr, TOK, 512, 2048);
  gemm_tile<2, 0><<<dim3(512 / 128, TOK / 128), 256, 0, stream>>>(
      c2, wb_adapt2, nullptr, adapt2b, a2, nullptr, 0, nullptr, nullptr, TOK, 512, 512);
  gemm_tile<2, 2><<<dim3(2048 / 128, TOK / 128), 256, 0, stream>>>(
      a2, wb_decomp2, nullptr, decomp2b, out, sel, 2, nullptr, nullptr, TOK, 2048, 512);

  // sel==0 tokens: exact fp32 passthrough of h
  copy_sel0<<<TOK, 256, 0, stream>>>(h, sel, out);
}